// Round 3
// baseline (471.738 us; speedup 1.0000x reference)
//
#include <hip/hip_runtime.h>

// Problem constants (complete bipartite proxy<->sample + self-loops)
#define PP 100    // proxies
#define NS 1024   // samples
#define NN 1124   // total nodes
#define DD 512    // feature dim
#define CC 100    // fc out dim
#define NBLK 256  // persistent blocks (1 per CU)
#define NTHR 256

__device__ __forceinline__ float lk(float v) { return v > 0.f ? v : 0.2f * v; }

// ---- device-scope grid barrier: monotone counter, no reset races ----
__device__ __forceinline__ void gbar(int* cnt, int phase) {
  __syncthreads();
  if (threadIdx.x == 0) {
    __threadfence();                       // publish this block's writes
    __hip_atomic_fetch_add(cnt, 1, __ATOMIC_ACQ_REL, __HIP_MEMORY_SCOPE_AGENT);
    const int tgt = NBLK * phase;
    while (__hip_atomic_load(cnt, __ATOMIC_ACQUIRE, __HIP_MEMORY_SCOPE_AGENT) < tgt)
      __builtin_amdgcn_s_sleep(1);
    __threadfence();                       // acquire side: invalidate caches
  }
  __syncthreads();
}

// ---- generic fp32 GEMM tile: C[BMxBN] at (row0,col0) = A[M,K]@B[K,N] (+bias,relu)
// lda = K, ldb = ldc = N. K % 32 == 0. 256 threads.
template<int BM, int BN, int TM, int TN, bool RELU>
__device__ void gemm_tile(const float* __restrict__ A, int M,
                          const float* __restrict__ B,
                          float* __restrict__ C, const float* __restrict__ bias,
                          int K, int N, int row0, int col0, float* smem)
{
  constexpr int BK  = 32;
  constexpr int NCT = BN / TN;
  constexpr int AF4 = BM * BK / 4;
  constexpr int BF4 = BK * BN / 4;
  constexpr int AFP = (AF4 + NTHR - 1) / NTHR;
  constexpr int BFP = (BF4 + NTHR - 1) / NTHR;
  static_assert(NCT * (BM / TM) == NTHR, "bad tile");
  float* As = smem;             // [BK][BM]
  float* Bs = smem + BK * BM;   // [BK][BN]
  const int t  = threadIdx.x;
  const int tn = t % NCT, tm = t / NCT;
  float4 aR[AFP], bR[BFP];

  auto loadA = [&](int kt) {
    #pragma unroll
    for (int p = 0; p < AFP; ++p) {
      int f = t + p * NTHR;
      float4 v = {0.f, 0.f, 0.f, 0.f};
      if (f < AF4) {
        int m = f / (BK / 4), k4 = (f % (BK / 4)) * 4;
        int r = row0 + m;
        if (r < M) v = *(const float4*)(A + (size_t)r * K + kt + k4);
      }
      aR[p] = v;
    }
  };
  auto loadB = [&](int kt) {
    #pragma unroll
    for (int p = 0; p < BFP; ++p) {
      int f = t + p * NTHR;
      float4 v = {0.f, 0.f, 0.f, 0.f};
      if (f < BF4) {
        int k = f / (BN / 4), c = col0 + (f % (BN / 4)) * 4;
        if (c + 3 < N) v = *(const float4*)(B + (size_t)(kt + k) * N + c);
      }
      bR[p] = v;
    }
  };
  auto storeT = [&]() {
    #pragma unroll
    for (int p = 0; p < AFP; ++p) {
      int f = t + p * NTHR;
      if (f < AF4) {
        int m = f / (BK / 4), k4 = (f % (BK / 4)) * 4;
        As[(k4 + 0) * BM + m] = aR[p].x;
        As[(k4 + 1) * BM + m] = aR[p].y;
        As[(k4 + 2) * BM + m] = aR[p].z;
        As[(k4 + 3) * BM + m] = aR[p].w;
      }
    }
    #pragma unroll
    for (int p = 0; p < BFP; ++p) {
      int f = t + p * NTHR;
      if (f < BF4) {
        int k = f / (BN / 4), c4 = (f % (BN / 4)) * 4;
        *(float4*)(Bs + k * BN + c4) = bR[p];
      }
    }
  };

  float acc[TM][TN] = {};
  loadA(0); loadB(0); storeT();
  __syncthreads();
  for (int kt = BK; kt < K + BK; kt += BK) {
    const bool more = (kt < K);
    if (more) { loadA(kt); loadB(kt); }
    #pragma unroll
    for (int k = 0; k < BK; ++k) {
      float a[TM], b[TN];
      if constexpr (TM == 4) {
        float4 v = *(const float4*)(As + k * BM + tm * 4);
        a[0] = v.x; a[1] = v.y; a[2] = v.z; a[3] = v.w;
      } else {
        float2 v = *(const float2*)(As + k * BM + tm * 2);
        a[0] = v.x; a[1] = v.y;
      }
      if constexpr (TN == 4) {
        float4 v = *(const float4*)(Bs + k * BN + tn * 4);
        b[0] = v.x; b[1] = v.y; b[2] = v.z; b[3] = v.w;
      } else {
        float2 v = *(const float2*)(Bs + k * BN + tn * 2);
        b[0] = v.x; b[1] = v.y;
      }
      #pragma unroll
      for (int i = 0; i < TM; ++i)
        #pragma unroll
        for (int j = 0; j < TN; ++j)
          acc[i][j] = fmaf(a[i], b[j], acc[i][j]);
    }
    __syncthreads();
    if (more) { storeT(); __syncthreads(); }
  }
  #pragma unroll
  for (int i = 0; i < TM; ++i) {
    int r = row0 + tm * TM + i;
    if (r >= M) continue;
    #pragma unroll
    for (int j = 0; j < TN; ++j) {
      int c = col0 + tn * TN + j;
      if (c >= N) continue;
      float v = acc[i][j] + bias[c];
      if constexpr (RELU) v = fmaxf(v, 0.f);
      C[(size_t)r * N + c] = v;
    }
  }
}

// ---- mix (sample destinations): M[s,:] = invZ_s * (Sum_p E[s,p]*Bp[p,:] + es_s*Bself[s,:])
// 64 dst-rows x 64 cols per tile, K = 100 proxies (+self in epilogue).
__device__ void mix_sample_tile(const float* __restrict__ ls, const float* __restrict__ ld,
                                const float* __restrict__ Bp,    // [100][DD] source feats
                                const float* __restrict__ Bself, // [1024][DD] self feats
                                float* __restrict__ Mout,        // row = sample idx
                                int row0, int col0, float* smem)
{
  float* Et   = smem;             // [128][64] exp weights, k-major (pad K to 128)
  float* Bs   = Et + 128 * 64;    // [32][64]
  float* lsP  = Bs + 32 * 64;     // [128]
  float* invZ = lsP + 128;        // [64]
  float* esfA = invZ + 64;        // [64]
  const int t = threadIdx.x;
  if (t < PP) lsP[t] = ls[t];
  __syncthreads();
  {                               // softmax stats: 4 threads per dst row
    const int r = t >> 2, q = t & 3;
    const int s = row0 + r;
    const float ldr = ld[PP + s];
    const float lself = ls[PP + s];
    float mx = -3.4e38f;
    for (int k = q; k < PP; k += 4) mx = fmaxf(mx, lsP[k]);
    mx = fmaxf(mx, __shfl_xor(mx, 1));
    mx = fmaxf(mx, __shfl_xor(mx, 2));
    mx = fmaxf(mx, lself);
    const float m = lk(mx + ldr);          // leaky is monotone: exact segment max
    float z = 0.f;
    for (int k = q; k < PP; k += 4) {
      float e = __expf(lk(lsP[k] + ldr) - m);
      Et[k * 64 + r] = e;
      z += e;
    }
    for (int k = PP + q; k < 128; k += 4) Et[k * 64 + r] = 0.f;
    const float es = __expf(lk(lself + ldr) - m);
    if (q == 0) z += es;
    z += __shfl_xor(z, 1);
    z += __shfl_xor(z, 2);
    if (q == 0) { invZ[r] = 1.f / z; esfA[r] = es; }
  }
  __syncthreads();
  const int tn = t % 16, tm = t / 16;
  float acc[4][4] = {};
  for (int k0 = 0; k0 < 128; k0 += 32) {
    #pragma unroll
    for (int p = 0; p < 2; ++p) {          // stage Bs[32][64]
      int f = t + p * 256;
      int k = f / 16, c = (f % 16) * 4;
      float4 v = {0.f, 0.f, 0.f, 0.f};
      int row = k0 + k;
      if (row < PP) v = *(const float4*)(Bp + (size_t)row * DD + col0 + c);
      *(float4*)(Bs + k * 64 + c) = v;
    }
    __syncthreads();
    #pragma unroll
    for (int k = 0; k < 32; ++k) {
      float4 av = *(const float4*)(Et + (k0 + k) * 64 + tm * 4);
      float4 bv = *(const float4*)(Bs + k * 64 + tn * 4);
      float a[4] = {av.x, av.y, av.z, av.w}, b[4] = {bv.x, bv.y, bv.z, bv.w};
      #pragma unroll
      for (int i = 0; i < 4; ++i)
        #pragma unroll
        for (int j = 0; j < 4; ++j)
          acc[i][j] = fmaf(a[i], b[j], acc[i][j]);
    }
    __syncthreads();
  }
  #pragma unroll
  for (int i = 0; i < 4; ++i) {
    const int rl = tm * 4 + i, s = row0 + rl;
    const float iz = invZ[rl], es = esfA[rl];
    float4 sv = *(const float4*)(Bself + (size_t)s * DD + col0 + tn * 4);
    float sf[4] = {sv.x, sv.y, sv.z, sv.w};
    #pragma unroll
    for (int j = 0; j < 4; ++j) {
      int c = col0 + tn * 4 + j;
      Mout[(size_t)s * DD + c] = (acc[i][j] + es * sf[j]) * iz;
    }
  }
}

// ---- mix (proxy destinations): M1[p,:] = invZ_p * (Sum_s E[p,s]*X[s,:] + es_p*Pr[p,:])
// 32 dst-rows x 32 cols per tile, K = 1024 samples, exp weights on the fly.
__device__ void mix_proxy_tile(const float* __restrict__ ls, const float* __restrict__ ld,
                               const float* __restrict__ X,   // [1024][DD]
                               const float* __restrict__ Pr,  // [100][DD] self feats
                               float* __restrict__ Mout,
                               int row0, int col0, float* smem)
{
  float* Et   = smem;             // [32][32] k-major chunk
  float* Bs   = Et + 32 * 32;     // [32][32]
  float* rowM = Bs + 32 * 32;     // [32]
  float* rowL = rowM + 32;        // [32]
  float* invZ = rowL + 32;        // [32]
  float* esfA = invZ + 32;        // [32]
  const int t = threadIdx.x;
  {                               // stats: 8 threads per dst row
    const int r = t >> 3, q = t & 7;
    const int p = row0 + r;
    const bool ok = (p < PP);
    const float ldr = ok ? ld[p] : 0.f;
    const float lself = ok ? ls[p] : 0.f;
    float mx = -3.4e38f;
    for (int k = q; k < NS; k += 8) mx = fmaxf(mx, ls[PP + k]);
    mx = fmaxf(mx, __shfl_xor(mx, 1));
    mx = fmaxf(mx, __shfl_xor(mx, 2));
    mx = fmaxf(mx, __shfl_xor(mx, 4));
    mx = fmaxf(mx, lself);
    const float m = lk(mx + ldr);
    float z = 0.f;
    for (int k = q; k < NS; k += 8) z += __expf(lk(ls[PP + k] + ldr) - m);
    const float es = __expf(lk(lself + ldr) - m);
    if (q == 0) z += es;
    z += __shfl_xor(z, 1);
    z += __shfl_xor(z, 2);
    z += __shfl_xor(z, 4);
    if (q == 0) { rowM[r] = m; rowL[r] = ldr; invZ[r] = 1.f / z; esfA[r] = es; }
  }
  __syncthreads();
  const int tn = t % 16, tm = t / 16;
  float acc[2][2] = {};
  for (int k0 = 0; k0 < NS; k0 += 32) {
    #pragma unroll
    for (int p4 = 0; p4 < 4; ++p4) {       // stage Et[32][32] on the fly
      int f = t + p4 * 256;
      int kk = f >> 5, rr = f & 31;
      float e = 0.f;
      if (row0 + rr < PP)
        e = __expf(lk(ls[PP + k0 + kk] + rowL[rr]) - rowM[rr]);
      Et[kk * 32 + rr] = e;
    }
    {                                       // stage Bs[32][32]
      int kk = t >> 3, cc = (t & 7) * 4;
      *(float4*)(Bs + kk * 32 + cc) =
          *(const float4*)(X + (size_t)(k0 + kk) * DD + col0 + cc);
    }
    __syncthreads();
    #pragma unroll
    for (int k = 0; k < 32; ++k) {
      float2 av = *(const float2*)(Et + k * 32 + tm * 2);
      float2 bv = *(const float2*)(Bs + k * 32 + tn * 2);
      acc[0][0] = fmaf(av.x, bv.x, acc[0][0]);
      acc[0][1] = fmaf(av.x, bv.y, acc[0][1]);
      acc[1][0] = fmaf(av.y, bv.x, acc[1][0]);
      acc[1][1] = fmaf(av.y, bv.y, acc[1][1]);
    }
    __syncthreads();
  }
  #pragma unroll
  for (int i = 0; i < 2; ++i) {
    const int rl = tm * 2 + i, p = row0 + rl;
    if (p >= PP) continue;
    const float iz = invZ[rl], es = esfA[rl];
    #pragma unroll
    for (int j = 0; j < 2; ++j) {
      int c = col0 + tn * 2 + j;
      Mout[(size_t)p * DD + c] = (acc[i][j] + es * Pr[(size_t)p * DD + c]) * iz;
    }
  }
}

// ---- logits: ls[r] = row_r . vs, ld[r] = row_r . vd  (one wave per row)
__device__ void lvec_phase(const float* __restrict__ A0, const float* __restrict__ A1,
                           int split, const float* __restrict__ vs,
                           const float* __restrict__ vd,
                           float* __restrict__ ls, float* __restrict__ ld)
{
  const int wid  = blockIdx.x * (NTHR / 64) + (threadIdx.x >> 6);
  const int lane = threadIdx.x & 63;
  const float4* s4 = (const float4*)vs;
  const float4* d4 = (const float4*)vd;
  for (int r = wid; r < NN; r += NBLK * (NTHR / 64)) {
    const float* row = (r < split) ? A0 + (size_t)r * DD : A1 + (size_t)(r - split) * DD;
    const float4* r4 = (const float4*)row;
    float4 v0 = r4[lane], v1 = r4[lane + 64];
    float4 a0 = s4[lane], a1 = s4[lane + 64];
    float4 b0 = d4[lane], b1 = d4[lane + 64];
    float s1 = v0.x * a0.x + v0.y * a0.y + v0.z * a0.z + v0.w * a0.w
             + v1.x * a1.x + v1.y * a1.y + v1.z * a1.z + v1.w * a1.w;
    float s2 = v0.x * b0.x + v0.y * b0.y + v0.z * b0.z + v0.w * b0.w
             + v1.x * b1.x + v1.y * b1.y + v1.z * b1.z + v1.w * b1.w;
    #pragma unroll
    for (int off = 32; off > 0; off >>= 1) {
      s1 += __shfl_down(s1, off);
      s2 += __shfl_down(s2, off);
    }
    if (lane == 0) { ls[r] = s1; ld[r] = s2; }
  }
}

// ---- v = W @ a for both layers (one wave per W row)
__device__ void matvec4(const float* __restrict__ W1, const float* __restrict__ as1,
                        const float* __restrict__ ad1,
                        const float* __restrict__ W2, const float* __restrict__ as2,
                        const float* __restrict__ ad2,
                        float* __restrict__ v1s, float* __restrict__ v1d,
                        float* __restrict__ v2s, float* __restrict__ v2d)
{
  const int wid  = blockIdx.x * (NTHR / 64) + (threadIdx.x >> 6);  // 0..1023
  const int lane = threadIdx.x & 63;
  const int r = wid & 511;
  const bool l1 = (wid < 512);
  const float* W = l1 ? W1 : W2;
  const float4* a4 = (const float4*)(l1 ? as1 : as2);
  const float4* b4 = (const float4*)(l1 ? ad1 : ad2);
  const float4* w4 = (const float4*)(W + (size_t)r * DD);
  float4 w0 = w4[lane], w1 = w4[lane + 64];
  float4 a0 = a4[lane], a1 = a4[lane + 64];
  float4 b0 = b4[lane], b1 = b4[lane + 64];
  float s1 = w0.x * a0.x + w0.y * a0.y + w0.z * a0.z + w0.w * a0.w
           + w1.x * a1.x + w1.y * a1.y + w1.z * a1.z + w1.w * a1.w;
  float s2 = w0.x * b0.x + w0.y * b0.y + w0.z * b0.z + w0.w * b0.w
           + w1.x * b1.x + w1.y * b1.y + w1.z * b1.z + w1.w * b1.w;
  #pragma unroll
  for (int off = 32; off > 0; off >>= 1) {
    s1 += __shfl_down(s1, off);
    s2 += __shfl_down(s2, off);
  }
  if (lane == 0) {
    (l1 ? v1s : v2s)[r] = s1;
    (l1 ? v1d : v2d)[r] = s2;
  }
}

__global__ __launch_bounds__(NTHR, 2) void fused_gat(
    const float* __restrict__ x, const float* __restrict__ prox,
    const float* __restrict__ W1, const float* __restrict__ as1,
    const float* __restrict__ ad1, const float* __restrict__ b1,
    const float* __restrict__ W2, const float* __restrict__ as2,
    const float* __restrict__ ad2, const float* __restrict__ b2,
    const float* __restrict__ fcw, const float* __restrict__ fcb,
    float* __restrict__ out,
    float* h1, float* M1, float* M2,
    float* ls1, float* ld1, float* ls2, float* ld2,
    float* v1s, float* v1d, float* v2s, float* v2d, int* cnt)
{
  __shared__ float smem[10496];   // 41 KB: max of all phase needs
  float* h2s = out + (size_t)NS * CC;   // layer-2 sample output region of d_out
  const int bid = blockIdx.x;

  // P0: v = W@a (both layers)
  matvec4(W1, as1, ad1, W2, as2, ad2, v1s, v1d, v2s, v2d);
  gbar(cnt, 1);
  // P1: layer-1 logits from inputs
  lvec_phase(prox, x, PP, v1s, v1d, ls1, ld1);
  gbar(cnt, 2);
  // P2: mix1 -> M1[1124][512]  (128 sample tiles + 64 proxy tiles)
  for (int tile = bid; tile < 192; tile += NBLK) {
    if (tile < 128)
      mix_sample_tile(ls1, ld1, prox, x, M1 + (size_t)PP * DD,
                      (tile >> 3) * 64, (tile & 7) * 64, smem);
    else {
      int tp = tile - 128;
      mix_proxy_tile(ls1, ld1, x, prox, M1, (tp >> 4) * 32, (tp & 15) * 32, smem);
    }
  }
  gbar(cnt, 3);
  // P3: h1 = relu(M1@W1 + b1)  (144 tiles)
  for (int tile = bid; tile < 144; tile += NBLK)
    gemm_tile<64, 64, 4, 4, true>(M1, NN, W1, h1, b1, DD, DD,
                                  (tile >> 3) * 64, (tile & 7) * 64, smem);
  gbar(cnt, 4);
  // P4: layer-2 logits from h1
  lvec_phase(h1, h1, NN, v2s, v2d, ls2, ld2);
  gbar(cnt, 5);
  // P5: mix2 -> M2[1024][512] (samples only; layer-2 proxy rows are dead code)
  for (int tile = bid; tile < 128; tile += NBLK)
    mix_sample_tile(ls2, ld2, h1, h1 + (size_t)PP * DD, M2,
                    (tile >> 3) * 64, (tile & 7) * 64, smem);
  gbar(cnt, 6);
  // P6: h2s = relu(M2@W2 + b2) -> straight into d_out's h region (128 tiles)
  for (int tile = bid; tile < 128; tile += NBLK)
    gemm_tile<64, 64, 4, 4, true>(M2, NS, W2, h2s, b2, DD, DD,
                                  (tile >> 3) * 64, (tile & 7) * 64, smem);
  gbar(cnt, 7);
  // P7: preds = h2s @ fcw + fcb (128 tiles of 32x32)
  for (int tile = bid; tile < 128; tile += NBLK)
    gemm_tile<32, 32, 2, 2, false>(h2s, NS, fcw, out, fcb, DD, CC,
                                   (tile >> 2) * 32, (tile & 3) * 32, smem);
}

extern "C" void kernel_launch(void* const* d_in, const int* in_sizes, int n_in,
                              void* d_out, int out_size, void* d_ws, size_t ws_size,
                              hipStream_t stream)
{
  const float* x    = (const float*)d_in[0];
  const float* prox = (const float*)d_in[1];
  const float* W1   = (const float*)d_in[2];
  const float* as1  = (const float*)d_in[3];
  const float* ad1  = (const float*)d_in[4];
  const float* b1   = (const float*)d_in[5];
  const float* W2   = (const float*)d_in[6];
  const float* as2  = (const float*)d_in[7];
  const float* ad2  = (const float*)d_in[8];
  const float* b2   = (const float*)d_in[9];
  const float* fcw  = (const float*)d_in[10];
  const float* fcb  = (const float*)d_in[11];
  float* out = (float*)d_out;

  int*   cnt  = (int*)d_ws;                      // barrier counter (256 B reserved)
  float* base = (float*)((char*)d_ws + 256);
  float* h1  = base;                             // [NN][DD]
  float* M1  = h1 + (size_t)NN * DD;             // [NN][DD]
  float* M2  = M1 + (size_t)NN * DD;             // [NS][DD]
  float* ls1 = M2 + (size_t)NS * DD;
  float* ld1 = ls1 + NN;
  float* ls2 = ld1 + NN;
  float* ld2 = ls2 + NN;
  float* v1s = ld2 + NN;
  float* v1d = v1s + DD;
  float* v2s = v1d + DD;
  float* v2d = v2s + DD;

  hipMemsetAsync(d_ws, 0, 256, stream);          // zero the barrier counter
  fused_gat<<<dim3(NBLK), dim3(NTHR), 0, stream>>>(
      x, prox, W1, as1, ad1, b1, W2, as2, ad2, b2, fcw, fcb, out,
      h1, M1, M2, ls1, ld1, ls2, ld2, v1s, v1d, v2s, v2d, cnt);
}

// Round 4
// 294.634 us; speedup vs baseline: 1.6011x; 1.6011x over previous
//
#include <hip/hip_runtime.h>

// Problem constants (complete bipartite proxy<->sample + self-loops)
#define PP 100    // proxies
#define NS 1024   // samples
#define NN 1124   // total nodes
#define DD 512    // feature dim
#define CC 100    // fc out dim
#define NBLK 256  // persistent blocks (1 per CU)
#define NTHR 256
#define NGRP 8
#define GSZ  (NBLK / NGRP)   // 32 blocks per arrival group

__device__ __forceinline__ float lk(float v) { return v > 0.f ? v : 0.2f * v; }

// ---- device-scope grid barrier, two-level arrival + single-writer release ---
// bar[g*32]  : per-group arrival counters (128 B apart, g = bid & 7)
// bar[256]   : root counter (leader adds)
// bar[288]   : release flag (single writer per phase; read-only polling)
// All counters are monotone (targets scale with phase) -> no reset races.
__device__ __forceinline__ void gbar(int* bar, int phase) {
  __syncthreads();
  if (threadIdx.x == 0) {
    __threadfence();                       // publish this block's writes (cross-XCD)
    const int g = blockIdx.x & (NGRP - 1);
    int v = __hip_atomic_fetch_add(&bar[g * 32], 1, __ATOMIC_RELAXED,
                                   __HIP_MEMORY_SCOPE_AGENT);
    if (v == GSZ * phase - 1) {            // last arrival in this group
      int r = __hip_atomic_fetch_add(&bar[256], 1, __ATOMIC_RELAXED,
                                     __HIP_MEMORY_SCOPE_AGENT);
      if (r == NGRP * phase - 1)           // last group overall -> release
        __hip_atomic_store(&bar[288], phase, __ATOMIC_RELEASE,
                           __HIP_MEMORY_SCOPE_AGENT);
    }
    while (__hip_atomic_load(&bar[288], __ATOMIC_RELAXED,
                             __HIP_MEMORY_SCOPE_AGENT) < phase)
      __builtin_amdgcn_s_sleep(8);         // ~512 cyc backoff: polls are rare + read-only
    __threadfence();                       // acquire side: invalidate local caches
  }
  __syncthreads();
}

// ---- generic fp32 GEMM tile: C[BMxBN] at (row0,col0) = A[M,K]@B[K,N] (+bias,relu)
// lda = K, ldb = ldc = N. K % 32 == 0. 256 threads.
template<int BM, int BN, int TM, int TN, bool RELU>
__device__ void gemm_tile(const float* __restrict__ A, int M,
                          const float* __restrict__ B,
                          float* __restrict__ C, const float* __restrict__ bias,
                          int K, int N, int row0, int col0, float* smem)
{
  constexpr int BK  = 32;
  constexpr int NCT = BN / TN;
  constexpr int AF4 = BM * BK / 4;
  constexpr int BF4 = BK * BN / 4;
  constexpr int AFP = (AF4 + NTHR - 1) / NTHR;
  constexpr int BFP = (BF4 + NTHR - 1) / NTHR;
  static_assert(NCT * (BM / TM) == NTHR, "bad tile");
  float* As = smem;             // [BK][BM]
  float* Bs = smem + BK * BM;   // [BK][BN]
  const int t  = threadIdx.x;
  const int tn = t % NCT, tm = t / NCT;
  float4 aR[AFP], bR[BFP];

  auto loadA = [&](int kt) {
    #pragma unroll
    for (int p = 0; p < AFP; ++p) {
      int f = t + p * NTHR;
      float4 v = {0.f, 0.f, 0.f, 0.f};
      if (f < AF4) {
        int m = f / (BK / 4), k4 = (f % (BK / 4)) * 4;
        int r = row0 + m;
        if (r < M) v = *(const float4*)(A + (size_t)r * K + kt + k4);
      }
      aR[p] = v;
    }
  };
  auto loadB = [&](int kt) {
    #pragma unroll
    for (int p = 0; p < BFP; ++p) {
      int f = t + p * NTHR;
      float4 v = {0.f, 0.f, 0.f, 0.f};
      if (f < BF4) {
        int k = f / (BN / 4), c = col0 + (f % (BN / 4)) * 4;
        if (c + 3 < N) v = *(const float4*)(B + (size_t)(kt + k) * N + c);
      }
      bR[p] = v;
    }
  };
  auto storeT = [&]() {
    #pragma unroll
    for (int p = 0; p < AFP; ++p) {
      int f = t + p * NTHR;
      if (f < AF4) {
        int m = f / (BK / 4), k4 = (f % (BK / 4)) * 4;
        As[(k4 + 0) * BM + m] = aR[p].x;
        As[(k4 + 1) * BM + m] = aR[p].y;
        As[(k4 + 2) * BM + m] = aR[p].z;
        As[(k4 + 3) * BM + m] = aR[p].w;
      }
    }
    #pragma unroll
    for (int p = 0; p < BFP; ++p) {
      int f = t + p * NTHR;
      if (f < BF4) {
        int k = f / (BN / 4), c4 = (f % (BN / 4)) * 4;
        *(float4*)(Bs + k * BN + c4) = bR[p];
      }
    }
  };

  float acc[TM][TN] = {};
  loadA(0); loadB(0); storeT();
  __syncthreads();
  for (int kt = BK; kt < K + BK; kt += BK) {
    const bool more = (kt < K);
    if (more) { loadA(kt); loadB(kt); }
    #pragma unroll
    for (int k = 0; k < BK; ++k) {
      float a[TM], b[TN];
      if constexpr (TM == 4) {
        float4 v = *(const float4*)(As + k * BM + tm * 4);
        a[0] = v.x; a[1] = v.y; a[2] = v.z; a[3] = v.w;
      } else {
        float2 v = *(const float2*)(As + k * BM + tm * 2);
        a[0] = v.x; a[1] = v.y;
      }
      if constexpr (TN == 4) {
        float4 v = *(const float4*)(Bs + k * BN + tn * 4);
        b[0] = v.x; b[1] = v.y; b[2] = v.z; b[3] = v.w;
      } else {
        float2 v = *(const float2*)(Bs + k * BN + tn * 2);
        b[0] = v.x; b[1] = v.y;
      }
      #pragma unroll
      for (int i = 0; i < TM; ++i)
        #pragma unroll
        for (int j = 0; j < TN; ++j)
          acc[i][j] = fmaf(a[i], b[j], acc[i][j]);
    }
    __syncthreads();
    if (more) { storeT(); __syncthreads(); }
  }
  #pragma unroll
  for (int i = 0; i < TM; ++i) {
    int r = row0 + tm * TM + i;
    if (r >= M) continue;
    #pragma unroll
    for (int j = 0; j < TN; ++j) {
      int c = col0 + tn * TN + j;
      if (c >= N) continue;
      float v = acc[i][j] + bias[c];
      if constexpr (RELU) v = fmaxf(v, 0.f);
      C[(size_t)r * N + c] = v;
    }
  }
}

// ---- mix (sample destinations): M[s,:] = invZ_s * (Sum_p E[s,p]*Bp[p,:] + es_s*Bself[s,:])
__device__ void mix_sample_tile(const float* __restrict__ ls, const float* __restrict__ ld,
                                const float* __restrict__ Bp,    // [100][DD] source feats
                                const float* __restrict__ Bself, // [1024][DD] self feats
                                float* __restrict__ Mout,        // row = sample idx
                                int row0, int col0, float* smem)
{
  float* Et   = smem;             // [128][64] exp weights, k-major (pad K to 128)
  float* Bs   = Et + 128 * 64;    // [32][64]
  float* lsP  = Bs + 32 * 64;     // [128]
  float* invZ = lsP + 128;        // [64]
  float* esfA = invZ + 64;        // [64]
  const int t = threadIdx.x;
  if (t < PP) lsP[t] = ls[t];
  __syncthreads();
  {                               // softmax stats: 4 threads per dst row
    const int r = t >> 2, q = t & 3;
    const int s = row0 + r;
    const float ldr = ld[PP + s];
    const float lself = ls[PP + s];
    float mx = -3.4e38f;
    for (int k = q; k < PP; k += 4) mx = fmaxf(mx, lsP[k]);
    mx = fmaxf(mx, __shfl_xor(mx, 1));
    mx = fmaxf(mx, __shfl_xor(mx, 2));
    mx = fmaxf(mx, lself);
    const float m = lk(mx + ldr);          // leaky is monotone: exact segment max
    float z = 0.f;
    for (int k = q; k < PP; k += 4) {
      float e = __expf(lk(lsP[k] + ldr) - m);
      Et[k * 64 + r] = e;
      z += e;
    }
    for (int k = PP + q; k < 128; k += 4) Et[k * 64 + r] = 0.f;
    const float es = __expf(lk(lself + ldr) - m);
    if (q == 0) z += es;
    z += __shfl_xor(z, 1);
    z += __shfl_xor(z, 2);
    if (q == 0) { invZ[r] = 1.f / z; esfA[r] = es; }
  }
  __syncthreads();
  const int tn = t % 16, tm = t / 16;
  float acc[4][4] = {};
  for (int k0 = 0; k0 < 128; k0 += 32) {
    #pragma unroll
    for (int p = 0; p < 2; ++p) {          // stage Bs[32][64]
      int f = t + p * 256;
      int k = f / 16, c = (f % 16) * 4;
      float4 v = {0.f, 0.f, 0.f, 0.f};
      int row = k0 + k;
      if (row < PP) v = *(const float4*)(Bp + (size_t)row * DD + col0 + c);
      *(float4*)(Bs + k * 64 + c) = v;
    }
    __syncthreads();
    #pragma unroll
    for (int k = 0; k < 32; ++k) {
      float4 av = *(const float4*)(Et + (k0 + k) * 64 + tm * 4);
      float4 bv = *(const float4*)(Bs + k * 64 + tn * 4);
      float a[4] = {av.x, av.y, av.z, av.w}, b[4] = {bv.x, bv.y, bv.z, bv.w};
      #pragma unroll
      for (int i = 0; i < 4; ++i)
        #pragma unroll
        for (int j = 0; j < 4; ++j)
          acc[i][j] = fmaf(a[i], b[j], acc[i][j]);
    }
    __syncthreads();
  }
  #pragma unroll
  for (int i = 0; i < 4; ++i) {
    const int rl = tm * 4 + i, s = row0 + rl;
    const float iz = invZ[rl], es = esfA[rl];
    float4 sv = *(const float4*)(Bself + (size_t)s * DD + col0 + tn * 4);
    float sf[4] = {sv.x, sv.y, sv.z, sv.w};
    #pragma unroll
    for (int j = 0; j < 4; ++j) {
      int c = col0 + tn * 4 + j;
      Mout[(size_t)s * DD + c] = (acc[i][j] + es * sf[j]) * iz;
    }
  }
}

// ---- mix (proxy destinations): M1[p,:] = invZ_p * (Sum_s E[p,s]*X[s,:] + es_p*Pr[p,:])
__device__ void mix_proxy_tile(const float* __restrict__ ls, const float* __restrict__ ld,
                               const float* __restrict__ X,   // [1024][DD]
                               const float* __restrict__ Pr,  // [100][DD] self feats
                               float* __restrict__ Mout,
                               int row0, int col0, float* smem)
{
  float* Et   = smem;             // [32][32] k-major chunk
  float* Bs   = Et + 32 * 32;     // [32][32]
  float* rowM = Bs + 32 * 32;     // [32]
  float* rowL = rowM + 32;        // [32]
  float* invZ = rowL + 32;        // [32]
  float* esfA = invZ + 32;        // [32]
  const int t = threadIdx.x;
  {                               // stats: 8 threads per dst row
    const int r = t >> 3, q = t & 7;
    const int p = row0 + r;
    const bool ok = (p < PP);
    const float ldr = ok ? ld[p] : 0.f;
    const float lself = ok ? ls[p] : 0.f;
    float mx = -3.4e38f;
    for (int k = q; k < NS; k += 8) mx = fmaxf(mx, ls[PP + k]);
    mx = fmaxf(mx, __shfl_xor(mx, 1));
    mx = fmaxf(mx, __shfl_xor(mx, 2));
    mx = fmaxf(mx, __shfl_xor(mx, 4));
    mx = fmaxf(mx, lself);
    const float m = lk(mx + ldr);
    float z = 0.f;
    for (int k = q; k < NS; k += 8) z += __expf(lk(ls[PP + k] + ldr) - m);
    const float es = __expf(lk(lself + ldr) - m);
    if (q == 0) z += es;
    z += __shfl_xor(z, 1);
    z += __shfl_xor(z, 2);
    z += __shfl_xor(z, 4);
    if (q == 0) { rowM[r] = m; rowL[r] = ldr; invZ[r] = 1.f / z; esfA[r] = es; }
  }
  __syncthreads();
  const int tn = t % 16, tm = t / 16;
  float acc[2][2] = {};
  for (int k0 = 0; k0 < NS; k0 += 32) {
    #pragma unroll
    for (int p4 = 0; p4 < 4; ++p4) {       // stage Et[32][32] on the fly
      int f = t + p4 * 256;
      int kk = f >> 5, rr = f & 31;
      float e = 0.f;
      if (row0 + rr < PP)
        e = __expf(lk(ls[PP + k0 + kk] + rowL[rr]) - rowM[rr]);
      Et[kk * 32 + rr] = e;
    }
    {                                       // stage Bs[32][32]
      int kk = t >> 3, cc = (t & 7) * 4;
      *(float4*)(Bs + kk * 32 + cc) =
          *(const float4*)(X + (size_t)(k0 + kk) * DD + col0 + cc);
    }
    __syncthreads();
    #pragma unroll
    for (int k = 0; k < 32; ++k) {
      float2 av = *(const float2*)(Et + k * 32 + tm * 2);
      float2 bv = *(const float2*)(Bs + k * 32 + tn * 2);
      acc[0][0] = fmaf(av.x, bv.x, acc[0][0]);
      acc[0][1] = fmaf(av.x, bv.y, acc[0][1]);
      acc[1][0] = fmaf(av.y, bv.x, acc[1][0]);
      acc[1][1] = fmaf(av.y, bv.y, acc[1][1]);
    }
    __syncthreads();
  }
  #pragma unroll
  for (int i = 0; i < 2; ++i) {
    const int rl = tm * 2 + i, p = row0 + rl;
    if (p >= PP) continue;
    const float iz = invZ[rl], es = esfA[rl];
    #pragma unroll
    for (int j = 0; j < 2; ++j) {
      int c = col0 + tn * 2 + j;
      Mout[(size_t)p * DD + c] = (acc[i][j] + es * Pr[(size_t)p * DD + c]) * iz;
    }
  }
}

// ---- logits: ls[r] = row_r . vs, ld[r] = row_r . vd  (one wave per row)
__device__ void lvec_phase(const float* __restrict__ A0, const float* __restrict__ A1,
                           int split, const float* __restrict__ vs,
                           const float* __restrict__ vd,
                           float* __restrict__ ls, float* __restrict__ ld)
{
  const int wid  = blockIdx.x * (NTHR / 64) + (threadIdx.x >> 6);
  const int lane = threadIdx.x & 63;
  const float4* s4 = (const float4*)vs;
  const float4* d4 = (const float4*)vd;
  for (int r = wid; r < NN; r += NBLK * (NTHR / 64)) {
    const float* row = (r < split) ? A0 + (size_t)r * DD : A1 + (size_t)(r - split) * DD;
    const float4* r4 = (const float4*)row;
    float4 v0 = r4[lane], v1 = r4[lane + 64];
    float4 a0 = s4[lane], a1 = s4[lane + 64];
    float4 b0 = d4[lane], b1 = d4[lane + 64];
    float s1 = v0.x * a0.x + v0.y * a0.y + v0.z * a0.z + v0.w * a0.w
             + v1.x * a1.x + v1.y * a1.y + v1.z * a1.z + v1.w * a1.w;
    float s2 = v0.x * b0.x + v0.y * b0.y + v0.z * b0.z + v0.w * b0.w
             + v1.x * b1.x + v1.y * b1.y + v1.z * b1.z + v1.w * b1.w;
    #pragma unroll
    for (int off = 32; off > 0; off >>= 1) {
      s1 += __shfl_down(s1, off);
      s2 += __shfl_down(s2, off);
    }
    if (lane == 0) { ls[r] = s1; ld[r] = s2; }
  }
}

// ---- v = W @ a for both layers (one wave per W row)
__device__ void matvec4(const float* __restrict__ W1, const float* __restrict__ as1,
                        const float* __restrict__ ad1,
                        const float* __restrict__ W2, const float* __restrict__ as2,
                        const float* __restrict__ ad2,
                        float* __restrict__ v1s, float* __restrict__ v1d,
                        float* __restrict__ v2s, float* __restrict__ v2d)
{
  const int wid  = blockIdx.x * (NTHR / 64) + (threadIdx.x >> 6);  // 0..1023
  const int lane = threadIdx.x & 63;
  const int r = wid & 511;
  const bool l1 = (wid < 512);
  const float* W = l1 ? W1 : W2;
  const float4* a4 = (const float4*)(l1 ? as1 : as2);
  const float4* b4 = (const float4*)(l1 ? ad1 : ad2);
  const float4* w4 = (const float4*)(W + (size_t)r * DD);
  float4 w0 = w4[lane], w1 = w4[lane + 64];
  float4 a0 = a4[lane], a1 = a4[lane + 64];
  float4 b0 = b4[lane], b1 = b4[lane + 64];
  float s1 = w0.x * a0.x + w0.y * a0.y + w0.z * a0.z + w0.w * a0.w
           + w1.x * a1.x + w1.y * a1.y + w1.z * a1.z + w1.w * a1.w;
  float s2 = w0.x * b0.x + w0.y * b0.y + w0.z * b0.z + w0.w * b0.w
           + w1.x * b1.x + w1.y * b1.y + w1.z * b1.z + w1.w * b1.w;
  #pragma unroll
  for (int off = 32; off > 0; off >>= 1) {
    s1 += __shfl_down(s1, off);
    s2 += __shfl_down(s2, off);
  }
  if (lane == 0) {
    (l1 ? v1s : v2s)[r] = s1;
    (l1 ? v1d : v2d)[r] = s2;
  }
}

__global__ __launch_bounds__(NTHR, 2) void fused_gat(
    const float* __restrict__ x, const float* __restrict__ prox,
    const float* __restrict__ W1, const float* __restrict__ as1,
    const float* __restrict__ ad1, const float* __restrict__ b1,
    const float* __restrict__ W2, const float* __restrict__ as2,
    const float* __restrict__ ad2, const float* __restrict__ b2,
    const float* __restrict__ fcw, const float* __restrict__ fcb,
    float* __restrict__ out,
    float* h1, float* M1, float* M2,
    float* ls1, float* ld1, float* ls2, float* ld2,
    float* v1s, float* v1d, float* v2s, float* v2d, int* bar)
{
  __shared__ float smem[10496];   // 41 KB: max of all phase needs
  float* h2s = out + (size_t)NS * CC;   // layer-2 sample output region of d_out
  const int bid = blockIdx.x;

  // P0: v = W@a (both layers)
  matvec4(W1, as1, ad1, W2, as2, ad2, v1s, v1d, v2s, v2d);
  gbar(bar, 1);
  // P1: layer-1 logits from inputs
  lvec_phase(prox, x, PP, v1s, v1d, ls1, ld1);
  gbar(bar, 2);
  // P2: mix1 -> M1[1124][512]  (128 sample tiles + 64 proxy tiles)
  for (int tile = bid; tile < 192; tile += NBLK) {
    if (tile < 128)
      mix_sample_tile(ls1, ld1, prox, x, M1 + (size_t)PP * DD,
                      (tile >> 3) * 64, (tile & 7) * 64, smem);
    else {
      int tp = tile - 128;
      mix_proxy_tile(ls1, ld1, x, prox, M1, (tp >> 4) * 32, (tp & 15) * 32, smem);
    }
  }
  gbar(bar, 3);
  // P3: h1 = relu(M1@W1 + b1)  (144 tiles)
  for (int tile = bid; tile < 144; tile += NBLK)
    gemm_tile<64, 64, 4, 4, true>(M1, NN, W1, h1, b1, DD, DD,
                                  (tile >> 3) * 64, (tile & 7) * 64, smem);
  gbar(bar, 4);
  // P4: layer-2 logits from h1
  lvec_phase(h1, h1, NN, v2s, v2d, ls2, ld2);
  gbar(bar, 5);
  // P5: mix2 -> M2[1024][512] (samples only; layer-2 proxy rows are dead code)
  for (int tile = bid; tile < 128; tile += NBLK)
    mix_sample_tile(ls2, ld2, h1, h1 + (size_t)PP * DD, M2,
                    (tile >> 3) * 64, (tile & 7) * 64, smem);
  gbar(bar, 6);
  // P6: h2s = relu(M2@W2 + b2) -> straight into d_out's h region (128 tiles)
  for (int tile = bid; tile < 128; tile += NBLK)
    gemm_tile<64, 64, 4, 4, true>(M2, NS, W2, h2s, b2, DD, DD,
                                  (tile >> 3) * 64, (tile & 7) * 64, smem);
  gbar(bar, 7);
  // P7: preds = h2s @ fcw + fcb (128 tiles of 32x32)
  for (int tile = bid; tile < 128; tile += NBLK)
    gemm_tile<32, 32, 2, 2, false>(h2s, NS, fcw, out, fcb, DD, CC,
                                   (tile >> 2) * 32, (tile & 3) * 32, smem);
}

extern "C" void kernel_launch(void* const* d_in, const int* in_sizes, int n_in,
                              void* d_out, int out_size, void* d_ws, size_t ws_size,
                              hipStream_t stream)
{
  const float* x    = (const float*)d_in[0];
  const float* prox = (const float*)d_in[1];
  const float* W1   = (const float*)d_in[2];
  const float* as1  = (const float*)d_in[3];
  const float* ad1  = (const float*)d_in[4];
  const float* b1   = (const float*)d_in[5];
  const float* W2   = (const float*)d_in[6];
  const float* as2  = (const float*)d_in[7];
  const float* ad2  = (const float*)d_in[8];
  const float* b2   = (const float*)d_in[9];
  const float* fcw  = (const float*)d_in[10];
  const float* fcb  = (const float*)d_in[11];
  float* out = (float*)d_out;

  int*   bar  = (int*)d_ws;                      // barrier region (4 KiB)
  float* base = (float*)((char*)d_ws + 4096);
  float* h1  = base;                             // [NN][DD]
  float* M1  = h1 + (size_t)NN * DD;             // [NN][DD]
  float* M2  = M1 + (size_t)NN * DD;             // [NS][DD]
  float* ls1 = M2 + (size_t)NS * DD;
  float* ld1 = ls1 + NN;
  float* ls2 = ld1 + NN;
  float* ld2 = ls2 + NN;
  float* v1s = ld2 + NN;
  float* v1d = v1s + DD;
  float* v2s = v1d + DD;
  float* v2d = v2s + DD;

  hipMemsetAsync(d_ws, 0, 4096, stream);         // zero barrier counters + flag
  fused_gat<<<dim3(NBLK), dim3(NTHR), 0, stream>>>(
      x, prox, W1, as1, ad1, b1, W2, as2, ad2, b2, fcw, fcb, out,
      h1, M1, M2, ls1, ld1, ls2, ld2, v1s, v1d, v2s, v2d, bar);
}

// Round 5
// 274.884 us; speedup vs baseline: 1.7161x; 1.0719x over previous
//
#include <hip/hip_runtime.h>

// Problem constants (complete bipartite proxy<->sample + self-loops)
#define PP 100    // proxies
#define NS 1024   // samples
#define NN 1124   // total nodes
#define DD 512    // feature dim
#define CC 100    // fc out dim
#define NTHR 256

__device__ __forceinline__ float lk(float v) { return v > 0.f ? v : 0.2f * v; }

// ============ GEMM: C[M,N] = A[M,K] @ B[K,N] (+bias, optional relu) =========
// 32x64 (or 32x32) tiles, 256 threads, register-prefetch double buffer.
template<int BM, int BN, int TM, int TN, bool RELU>
__global__ __launch_bounds__(NTHR) void gemm_k(
    const float* __restrict__ A, int M,
    const float* __restrict__ B,
    float* __restrict__ C, const float* __restrict__ bias,
    int K, int N)
{
  constexpr int BK  = 32;
  constexpr int NCT = BN / TN;
  constexpr int AF4 = BM * BK / 4;
  constexpr int BF4 = BK * BN / 4;
  constexpr int AFP = (AF4 + NTHR - 1) / NTHR;
  constexpr int BFP = (BF4 + NTHR - 1) / NTHR;
  static_assert(NCT * (BM / TM) == NTHR, "bad tile");
  __shared__ float As[BK * BM];   // k-major: As[k*BM+m]
  __shared__ float Bs[BK * BN];
  const int row0 = blockIdx.y * BM;
  const int col0 = blockIdx.x * BN;
  const int t  = threadIdx.x;
  const int tn = t % NCT, tm = t / NCT;
  float4 aR[AFP], bR[BFP];

  auto loadA = [&](int kt) {
    #pragma unroll
    for (int p = 0; p < AFP; ++p) {
      int f = t + p * NTHR;
      float4 v = {0.f, 0.f, 0.f, 0.f};
      if (f < AF4) {
        int m = f / (BK / 4), k4 = (f % (BK / 4)) * 4;
        int r = row0 + m;
        if (r < M) v = *(const float4*)(A + (size_t)r * K + kt + k4);
      }
      aR[p] = v;
    }
  };
  auto loadB = [&](int kt) {
    #pragma unroll
    for (int p = 0; p < BFP; ++p) {
      int f = t + p * NTHR;
      float4 v = {0.f, 0.f, 0.f, 0.f};
      if (f < BF4) {
        int k = f / (BN / 4), c = col0 + (f % (BN / 4)) * 4;
        if (c + 3 < N) v = *(const float4*)(B + (size_t)(kt + k) * N + c);
      }
      bR[p] = v;
    }
  };
  auto storeT = [&]() {
    #pragma unroll
    for (int p = 0; p < AFP; ++p) {
      int f = t + p * NTHR;
      if (f < AF4) {
        int m = f / (BK / 4), k4 = (f % (BK / 4)) * 4;
        As[(k4 + 0) * BM + m] = aR[p].x;
        As[(k4 + 1) * BM + m] = aR[p].y;
        As[(k4 + 2) * BM + m] = aR[p].z;
        As[(k4 + 3) * BM + m] = aR[p].w;
      }
    }
    #pragma unroll
    for (int p = 0; p < BFP; ++p) {
      int f = t + p * NTHR;
      if (f < BF4) {
        int k = f / (BN / 4), c4 = (f % (BN / 4)) * 4;
        *(float4*)(Bs + k * BN + c4) = bR[p];
      }
    }
  };

  float acc[TM][TN] = {};
  loadA(0); loadB(0); storeT();
  __syncthreads();
  for (int kt = BK; kt < K + BK; kt += BK) {
    const bool more = (kt < K);
    if (more) { loadA(kt); loadB(kt); }
    #pragma unroll
    for (int k = 0; k < BK; ++k) {
      float a[TM], b[TN];
      if constexpr (TM == 2) {
        float2 v = *(const float2*)(As + k * BM + tm * 2);
        a[0] = v.x; a[1] = v.y;
      } else {
        float4 v = *(const float4*)(As + k * BM + tm * 4);
        a[0] = v.x; a[1] = v.y; a[2] = v.z; a[3] = v.w;
      }
      if constexpr (TN == 4) {
        float4 v = *(const float4*)(Bs + k * BN + tn * 4);
        b[0] = v.x; b[1] = v.y; b[2] = v.z; b[3] = v.w;
      } else {
        float2 v = *(const float2*)(Bs + k * BN + tn * 2);
        b[0] = v.x; b[1] = v.y;
      }
      #pragma unroll
      for (int i = 0; i < TM; ++i)
        #pragma unroll
        for (int j = 0; j < TN; ++j)
          acc[i][j] = fmaf(a[i], b[j], acc[i][j]);
    }
    __syncthreads();
    if (more) { storeT(); __syncthreads(); }
  }
  #pragma unroll
  for (int i = 0; i < TM; ++i) {
    int r = row0 + tm * TM + i;
    if (r >= M) continue;
    #pragma unroll
    for (int j = 0; j < TN; ++j) {
      int c = col0 + tn * TN + j;
      if (c >= N) continue;
      float v = acc[i][j] + bias[c];
      if constexpr (RELU) v = fmaxf(v, 0.f);
      C[(size_t)r * N + c] = v;
    }
  }
}

// ============ mix, sample destinations: 32 rows x 64 cols per block =========
// M[s,:] = invZ_s * (Sum_p E[s,p]*Bp[p,:] + es_s*Bself[s,:])
__device__ __forceinline__ void mixS_tile(
    const float* __restrict__ ls, const float* __restrict__ ld,
    const float* __restrict__ Bp,    // [100][DD] proxy-source feats
    const float* __restrict__ Bself, // [1024][DD] self feats
    float* __restrict__ Mout, int row0, int col0, float* smem)
{
  float* Et    = smem;              // [32 k][32 r] chunk
  float* Bs    = Et + 32 * 32;      // [32 k][64 c]
  float* lsP   = Bs + 32 * 64;      // [100]
  float* rowM  = lsP + 100;         // [32] softmax max (post-leaky)
  float* rowL  = rowM + 32;         // [32] ld of row
  float* rowIZ = rowL + 32;         // [32] 1/Z
  float* rowES = rowIZ + 32;        // [32] self exp
  const int t = threadIdx.x;
  if (t < PP) lsP[t] = ls[t];
  __syncthreads();
  {                                  // stats: 8 threads per dst row
    const int r = t >> 3, q = t & 7;
    const int s = row0 + r;
    const float ldr = ld[PP + s];
    const float lself = ls[PP + s];
    float mx = -3.4e38f;
    for (int k = q; k < PP; k += 8) mx = fmaxf(mx, lsP[k]);
    mx = fmaxf(mx, __shfl_xor(mx, 1));
    mx = fmaxf(mx, __shfl_xor(mx, 2));
    mx = fmaxf(mx, __shfl_xor(mx, 4));
    mx = fmaxf(mx, lself);
    const float m = lk(mx + ldr);    // leaky monotone -> exact segment max
    float z = 0.f;
    for (int k = q; k < PP; k += 8) z += __expf(lk(lsP[k] + ldr) - m);
    const float es = __expf(lk(lself + ldr) - m);
    if (q == 0) z += es;
    z += __shfl_xor(z, 1);
    z += __shfl_xor(z, 2);
    z += __shfl_xor(z, 4);
    if (q == 0) {
      rowM[r] = m; rowL[r] = ldr; rowIZ[r] = 1.f / z; rowES[r] = es;
    }
  }
  __syncthreads();
  const int tn = t % 16, tm = t / 16;
  float acc[2][4] = {};
  for (int k0 = 0; k0 < 128; k0 += 32) {     // K=100 padded to 128
    #pragma unroll
    for (int p = 0; p < 4; ++p) {            // Et[32][32] on the fly
      int f = t + p * 256;
      int kk = f >> 5, rr = f & 31;
      float e = 0.f;
      if (k0 + kk < PP)
        e = __expf(lk(lsP[k0 + kk] + rowL[rr]) - rowM[rr]);
      Et[kk * 32 + rr] = e;
    }
    #pragma unroll
    for (int p = 0; p < 2; ++p) {            // Bs[32][64]
      int f = t + p * 256;
      int kk = f / 16, cc = (f % 16) * 4;
      float4 v = {0.f, 0.f, 0.f, 0.f};
      if (k0 + kk < PP) v = *(const float4*)(Bp + (size_t)(k0 + kk) * DD + col0 + cc);
      *(float4*)(Bs + kk * 64 + cc) = v;
    }
    __syncthreads();
    #pragma unroll
    for (int k = 0; k < 32; ++k) {
      float2 av = *(const float2*)(Et + k * 32 + tm * 2);
      float4 bv = *(const float4*)(Bs + k * 64 + tn * 4);
      float a[2] = {av.x, av.y}, b[4] = {bv.x, bv.y, bv.z, bv.w};
      #pragma unroll
      for (int i = 0; i < 2; ++i)
        #pragma unroll
        for (int j = 0; j < 4; ++j)
          acc[i][j] = fmaf(a[i], b[j], acc[i][j]);
    }
    __syncthreads();
  }
  #pragma unroll
  for (int i = 0; i < 2; ++i) {
    const int rl = tm * 2 + i, s = row0 + rl;
    const float iz = rowIZ[rl], es = rowES[rl];
    float4 sv = *(const float4*)(Bself + (size_t)s * DD + col0 + tn * 4);
    float sf[4] = {sv.x, sv.y, sv.z, sv.w};
    #pragma unroll
    for (int j = 0; j < 4; ++j)
      Mout[(size_t)s * DD + col0 + tn * 4 + j] = (acc[i][j] + es * sf[j]) * iz;
  }
}

// ============ mix, proxy destinations: 32 rows x 32 cols per block ==========
__device__ __forceinline__ void mixP_tile(
    const float* __restrict__ ls, const float* __restrict__ ld,
    const float* __restrict__ X,   // [1024][DD]
    const float* __restrict__ Pr,  // [100][DD]
    float* __restrict__ Mout, int row0, int col0, float* smem)
{
  float* Et    = smem;             // [32 k][32 r]
  float* Bs    = Et + 32 * 32;     // [32 k][32 c]
  float* rowM  = Bs + 32 * 32;
  float* rowL  = rowM + 32;
  float* rowIZ = rowL + 32;
  float* rowES = rowIZ + 32;
  const int t = threadIdx.x;
  {                                // stats: 8 threads per dst row
    const int r = t >> 3, q = t & 7;
    const int p = row0 + r;
    const bool ok = (p < PP);
    const float ldr = ok ? ld[p] : 0.f;
    const float lself = ok ? ls[p] : 0.f;
    float mx = -3.4e38f;
    for (int k = q; k < NS; k += 8) mx = fmaxf(mx, ls[PP + k]);
    mx = fmaxf(mx, __shfl_xor(mx, 1));
    mx = fmaxf(mx, __shfl_xor(mx, 2));
    mx = fmaxf(mx, __shfl_xor(mx, 4));
    mx = fmaxf(mx, lself);
    const float m = lk(mx + ldr);
    float z = 0.f;
    for (int k = q; k < NS; k += 8) z += __expf(lk(ls[PP + k] + ldr) - m);
    const float es = __expf(lk(lself + ldr) - m);
    if (q == 0) z += es;
    z += __shfl_xor(z, 1);
    z += __shfl_xor(z, 2);
    z += __shfl_xor(z, 4);
    if (q == 0) { rowM[r] = m; rowL[r] = ldr; rowIZ[r] = 1.f / z; rowES[r] = es; }
  }
  __syncthreads();
  const int tn = t % 16, tm = t / 16;
  float acc[2][2] = {};
  for (int k0 = 0; k0 < NS; k0 += 32) {
    #pragma unroll
    for (int p4 = 0; p4 < 4; ++p4) {         // Et chunk on the fly
      int f = t + p4 * 256;
      int kk = f >> 5, rr = f & 31;
      float e = 0.f;
      if (row0 + rr < PP)
        e = __expf(lk(ls[PP + k0 + kk] + rowL[rr]) - rowM[rr]);
      Et[kk * 32 + rr] = e;
    }
    {                                         // Bs[32][32]
      int kk = t >> 3, cc = (t & 7) * 4;
      *(float4*)(Bs + kk * 32 + cc) =
          *(const float4*)(X + (size_t)(k0 + kk) * DD + col0 + cc);
    }
    __syncthreads();
    #pragma unroll
    for (int k = 0; k < 32; ++k) {
      float2 av = *(const float2*)(Et + k * 32 + tm * 2);
      float2 bv = *(const float2*)(Bs + k * 32 + tn * 2);
      acc[0][0] = fmaf(av.x, bv.x, acc[0][0]);
      acc[0][1] = fmaf(av.x, bv.y, acc[0][1]);
      acc[1][0] = fmaf(av.y, bv.x, acc[1][0]);
      acc[1][1] = fmaf(av.y, bv.y, acc[1][1]);
    }
    __syncthreads();
  }
  #pragma unroll
  for (int i = 0; i < 2; ++i) {
    const int rl = tm * 2 + i, p = row0 + rl;
    if (p >= PP) continue;
    const float iz = rowIZ[rl], es = rowES[rl];
    #pragma unroll
    for (int j = 0; j < 2; ++j) {
      int c = col0 + tn * 2 + j;
      Mout[(size_t)p * DD + c] = (acc[i][j] + es * Pr[(size_t)p * DD + c]) * iz;
    }
  }
}

// mix layer 1: blocks [0,256) sample tiles -> M1 sample rows; [256,320) proxy
__global__ __launch_bounds__(NTHR) void mix1_k(
    const float* __restrict__ ls, const float* __restrict__ ld,
    const float* __restrict__ x, const float* __restrict__ prox,
    float* __restrict__ M1)
{
  __shared__ float smem[3300];
  const int b = blockIdx.x;
  if (b < 256)
    mixS_tile(ls, ld, prox, x, M1 + (size_t)PP * DD,
              (b >> 3) * 32, (b & 7) * 64, smem);
  else {
    int tp = b - 256;
    mixP_tile(ls, ld, x, prox, M1, (tp >> 4) * 32, (tp & 15) * 32, smem);
  }
}

// mix layer 2: sample destinations only (layer-2 proxy rows are dead code)
__global__ __launch_bounds__(NTHR) void mix2_k(
    const float* __restrict__ ls, const float* __restrict__ ld,
    const float* __restrict__ h1, float* __restrict__ M2)
{
  __shared__ float smem[3300];
  const int b = blockIdx.x;
  mixS_tile(ls, ld, h1, h1 + (size_t)PP * DD, M2,
            (b >> 3) * 32, (b & 7) * 64, smem);
}

// ============ v = W @ a for both layers (one wave per W row) ================
__global__ __launch_bounds__(NTHR) void matvec_k(
    const float* __restrict__ W1, const float* __restrict__ as1,
    const float* __restrict__ ad1,
    const float* __restrict__ W2, const float* __restrict__ as2,
    const float* __restrict__ ad2,
    float* __restrict__ v1s, float* __restrict__ v1d,
    float* __restrict__ v2s, float* __restrict__ v2d)
{
  const int wid  = blockIdx.x * 4 + (threadIdx.x >> 6);  // 0..1023
  const int lane = threadIdx.x & 63;
  const int r = wid & 511;
  const bool l1 = (wid < 512);
  const float* W = l1 ? W1 : W2;
  const float4* a4 = (const float4*)(l1 ? as1 : as2);
  const float4* b4 = (const float4*)(l1 ? ad1 : ad2);
  const float4* w4 = (const float4*)(W + (size_t)r * DD);
  float4 w0 = w4[lane], w1 = w4[lane + 64];
  float4 a0 = a4[lane], a1 = a4[lane + 64];
  float4 b0 = b4[lane], b1 = b4[lane + 64];
  float s1 = w0.x * a0.x + w0.y * a0.y + w0.z * a0.z + w0.w * a0.w
           + w1.x * a1.x + w1.y * a1.y + w1.z * a1.z + w1.w * a1.w;
  float s2 = w0.x * b0.x + w0.y * b0.y + w0.z * b0.z + w0.w * b0.w
           + w1.x * b1.x + w1.y * b1.y + w1.z * b1.z + w1.w * b1.w;
  #pragma unroll
  for (int off = 32; off > 0; off >>= 1) {
    s1 += __shfl_down(s1, off);
    s2 += __shfl_down(s2, off);
  }
  if (lane == 0) {
    (l1 ? v1s : v2s)[r] = s1;
    (l1 ? v1d : v2d)[r] = s2;
  }
}

// ============ logits: ls[r]=row_r.vs, ld[r]=row_r.vd (one wave per row) =====
__global__ __launch_bounds__(NTHR) void lvec_k(
    const float* __restrict__ A0, const float* __restrict__ A1, int split,
    const float* __restrict__ vs, const float* __restrict__ vd,
    float* __restrict__ ls, float* __restrict__ ld)
{
  const int r    = blockIdx.x * 4 + (threadIdx.x >> 6);
  const int lane = threadIdx.x & 63;
  if (r >= NN) return;
  const float* row = (r < split) ? A0 + (size_t)r * DD : A1 + (size_t)(r - split) * DD;
  const float4* r4 = (const float4*)row;
  const float4* s4 = (const float4*)vs;
  const float4* d4 = (const float4*)vd;
  float4 v0 = r4[lane], v1 = r4[lane + 64];
  float4 a0 = s4[lane], a1 = s4[lane + 64];
  float4 b0 = d4[lane], b1 = d4[lane + 64];
  float s1 = v0.x * a0.x + v0.y * a0.y + v0.z * a0.z + v0.w * a0.w
           + v1.x * a1.x + v1.y * a1.y + v1.z * a1.z + v1.w * a1.w;
  float s2 = v0.x * b0.x + v0.y * b0.y + v0.z * b0.z + v0.w * b0.w
           + v1.x * b1.x + v1.y * b1.y + v1.z * b1.z + v1.w * b1.w;
  #pragma unroll
  for (int off = 32; off > 0; off >>= 1) {
    s1 += __shfl_down(s1, off);
    s2 += __shfl_down(s2, off);
  }
  if (lane == 0) { ls[r] = s1; ld[r] = s2; }
}

extern "C" void kernel_launch(void* const* d_in, const int* in_sizes, int n_in,
                              void* d_out, int out_size, void* d_ws, size_t ws_size,
                              hipStream_t stream)
{
  const float* x    = (const float*)d_in[0];
  const float* prox = (const float*)d_in[1];
  const float* W1   = (const float*)d_in[2];
  const float* as1  = (const float*)d_in[3];
  const float* ad1  = (const float*)d_in[4];
  const float* b1   = (const float*)d_in[5];
  const float* W2   = (const float*)d_in[6];
  const float* as2  = (const float*)d_in[7];
  const float* ad2  = (const float*)d_in[8];
  const float* b2   = (const float*)d_in[9];
  const float* fcw  = (const float*)d_in[10];
  const float* fcb  = (const float*)d_in[11];
  float* out = (float*)d_out;

  float* h1  = (float*)d_ws;                     // [NN][DD]
  float* M1  = h1 + (size_t)NN * DD;             // [NN][DD]
  float* M2  = M1 + (size_t)NN * DD;             // [NS][DD]
  float* ls1 = M2 + (size_t)NS * DD;
  float* ld1 = ls1 + NN;
  float* ls2 = ld1 + NN;
  float* ld2 = ls2 + NN;
  float* v1s = ld2 + NN;
  float* v1d = v1s + DD;
  float* v2s = v1d + DD;
  float* v2d = v2s + DD;
  float* h2s = out + (size_t)NS * CC;            // layer-2 sample out in d_out

  dim3 blk(NTHR);
  // P0: weight-side matvecs for both layers
  matvec_k<<<dim3(256), blk, 0, stream>>>(W1, as1, ad1, W2, as2, ad2,
                                          v1s, v1d, v2s, v2d);
  // P1: layer-1 logits from raw inputs
  lvec_k<<<dim3(281), blk, 0, stream>>>(prox, x, PP, v1s, v1d, ls1, ld1);
  // P2: mix1 -> M1[1124][512]
  mix1_k<<<dim3(320), blk, 0, stream>>>(ls1, ld1, x, prox, M1);
  // P3: h1 = relu(M1@W1 + b1)   (32x64 tiles: 8 x 36 = 288 blocks)
  gemm_k<32, 64, 2, 4, true><<<dim3(8, 36), blk, 0, stream>>>(
      M1, NN, W1, h1, b1, DD, DD);
  // P4: layer-2 logits from h1
  lvec_k<<<dim3(281), blk, 0, stream>>>(h1, h1, NN, v2s, v2d, ls2, ld2);
  // P5: mix2 -> M2[1024][512] (samples only)
  mix2_k<<<dim3(256), blk, 0, stream>>>(ls2, ld2, h1, M2);
  // P6: h2s = relu(M2@W2 + b2) straight into d_out  (8 x 32 = 256 blocks)
  gemm_k<32, 64, 2, 4, true><<<dim3(8, 32), blk, 0, stream>>>(
      M2, NS, W2, h2s, b2, DD, DD);
  // P7: preds = h2s @ fcw + fcb  (32x32 tiles: 4 x 32 = 128 blocks)
  gemm_k<32, 32, 2, 2, false><<<dim3(4, 32), blk, 0, stream>>>(
      h2s, NS, fcw, out, fcb, DD, CC);
}

// Round 6
// 205.133 us; speedup vs baseline: 2.2997x; 1.3400x over previous
//
#include <hip/hip_runtime.h>

// Problem constants (complete bipartite proxy<->sample + self-loops)
#define PP 100    // proxies
#define NS 1024   // samples
#define NN 1124   // total nodes
#define DD 512    // feature dim
#define CC 100    // fc out dim
#define NTHR 256

__device__ __forceinline__ float lk(float v) { return v > 0.f ? v : 0.2f * v; }

// ============ GEMM core (device fn): C tile = A[M,K]@B[K,N] ================
// Krows: valid rows of B (rows >= Krows read as 0). k-major LDS, reg prefetch.
// EPI: v = (acc + es[r]*S[r*N+c]) * iz[r];  then +bias, then relu (if enabled).
template<int BM, int BN, int TM, int TN, bool RELU, bool EPI>
__device__ __forceinline__ void gemm_dev(
    const float* __restrict__ A, int M,
    const float* __restrict__ B, int Krows,
    float* __restrict__ C, const float* __restrict__ bias,
    int K, int N,
    const float* __restrict__ S, const float* __restrict__ es,
    const float* __restrict__ iz,
    int row0, int col0, float* smem)
{
  constexpr int BK  = 32;
  constexpr int NCT = BN / TN;
  constexpr int AF4 = BM * BK / 4;
  constexpr int BF4 = BK * BN / 4;
  constexpr int AFP = (AF4 + NTHR - 1) / NTHR;
  constexpr int BFP = (BF4 + NTHR - 1) / NTHR;
  static_assert(NCT * (BM / TM) == NTHR, "bad tile");
  float* As = smem;            // [BK][BM] k-major
  float* Bs = smem + BK * BM;  // [BK][BN]
  const int t  = threadIdx.x;
  const int tn = t % NCT, tm = t / NCT;
  float4 aR[AFP], bR[BFP];

  auto loadA = [&](int kt) {
    #pragma unroll
    for (int p = 0; p < AFP; ++p) {
      int f = t + p * NTHR;
      float4 v = {0.f, 0.f, 0.f, 0.f};
      if (f < AF4) {
        int m = f / (BK / 4), k4 = (f % (BK / 4)) * 4;
        int r = row0 + m;
        if (r < M) v = *(const float4*)(A + (size_t)r * K + kt + k4);
      }
      aR[p] = v;
    }
  };
  auto loadB = [&](int kt) {
    #pragma unroll
    for (int p = 0; p < BFP; ++p) {
      int f = t + p * NTHR;
      float4 v = {0.f, 0.f, 0.f, 0.f};
      if (f < BF4) {
        int k = kt + f / (BN / 4), c = col0 + (f % (BN / 4)) * 4;
        if (k < Krows && c + 3 < N) v = *(const float4*)(B + (size_t)k * N + c);
      }
      bR[p] = v;
    }
  };
  auto storeT = [&]() {
    #pragma unroll
    for (int p = 0; p < AFP; ++p) {
      int f = t + p * NTHR;
      if (f < AF4) {
        int m = f / (BK / 4), k4 = (f % (BK / 4)) * 4;
        As[(k4 + 0) * BM + m] = aR[p].x;
        As[(k4 + 1) * BM + m] = aR[p].y;
        As[(k4 + 2) * BM + m] = aR[p].z;
        As[(k4 + 3) * BM + m] = aR[p].w;
      }
    }
    #pragma unroll
    for (int p = 0; p < BFP; ++p) {
      int f = t + p * NTHR;
      if (f < BF4) {
        int k = f / (BN / 4), c4 = (f % (BN / 4)) * 4;
        *(float4*)(Bs + k * BN + c4) = bR[p];
      }
    }
  };

  float acc[TM][TN] = {};
  loadA(0); loadB(0); storeT();
  __syncthreads();
  for (int kt = BK; kt < K + BK; kt += BK) {
    const bool more = (kt < K);
    if (more) { loadA(kt); loadB(kt); }
    #pragma unroll
    for (int k = 0; k < BK; ++k) {
      float a[TM], b[TN];
      if constexpr (TM == 1) {
        a[0] = As[k * BM + tm];
      } else if constexpr (TM == 2) {
        float2 v = *(const float2*)(As + k * BM + tm * 2);
        a[0] = v.x; a[1] = v.y;
      } else {
        float4 v = *(const float4*)(As + k * BM + tm * 4);
        a[0] = v.x; a[1] = v.y; a[2] = v.z; a[3] = v.w;
      }
      float4 bv = *(const float4*)(Bs + k * BN + tn * 4);
      b[0] = bv.x; b[1] = bv.y; b[2] = bv.z; b[3] = bv.w;
      #pragma unroll
      for (int i = 0; i < TM; ++i)
        #pragma unroll
        for (int j = 0; j < TN; ++j)
          acc[i][j] = fmaf(a[i], b[j], acc[i][j]);
    }
    __syncthreads();
    if (more) { storeT(); __syncthreads(); }
  }
  #pragma unroll
  for (int i = 0; i < TM; ++i) {
    int r = row0 + tm * TM + i;
    if (r >= M) continue;
    float esr = 0.f, izr = 0.f;
    if constexpr (EPI) { esr = es[r]; izr = iz[r]; }
    #pragma unroll
    for (int j = 0; j < TN; ++j) {
      int c = col0 + tn * TN + j;
      if (c >= N) continue;
      float v = acc[i][j];
      if constexpr (EPI) v = (v + esr * S[(size_t)r * N + c]) * izr;
      if (bias) v += bias[c];
      if constexpr (RELU) v = fmaxf(v, 0.f);
      C[(size_t)r * N + c] = v;
    }
  }
}

// plain GEMM kernel (transforms + fc): grid (col_tiles, row_tiles)
template<int BM, int BN, int TM, bool RELU>
__global__ __launch_bounds__(NTHR) void gemm_k(
    const float* __restrict__ A, int M, const float* __restrict__ B,
    float* __restrict__ C, const float* __restrict__ bias, int K, int N)
{
  __shared__ float smem[32 * BM + 32 * BN];
  gemm_dev<BM, BN, TM, 4, RELU, false>(
      A, M, B, K, C, bias, K, N, nullptr, nullptr, nullptr,
      blockIdx.y * BM, blockIdx.x * BN, smem);
}

// layer-1 aggregation: blocks [0,256) sample tiles, [256,312) proxy tiles
__global__ __launch_bounds__(NTHR) void agg1_k(
    const float* __restrict__ Es, const float* __restrict__ Ep,
    const float* __restrict__ x, const float* __restrict__ prox,
    const float* __restrict__ esS, const float* __restrict__ izS,
    const float* __restrict__ esP, const float* __restrict__ izP,
    float* __restrict__ M1)
{
  __shared__ float smem[32 * 32 + 32 * 64];
  const int b = blockIdx.x;
  if (b < 256) {
    // M1_samp[1024,512] = Es[1024,128] @ prox(100 rows; pad->0) , epi self=x
    gemm_dev<32, 64, 2, 4, false, true>(
        Es, NS, prox, PP, M1 + (size_t)PP * DD, nullptr, 128, DD,
        x, esS, izS, (b >> 3) * 32, (b & 7) * 64, smem);
  } else {
    // M1_prox[100,512] = Ep[100,1024] @ x , epi self=prox
    int b2 = b - 256;
    gemm_dev<16, 64, 1, 4, false, true>(
        Ep, PP, x, NS, M1, nullptr, NS, DD,
        prox, esP, izP, (b2 >> 3) * 16, (b2 & 7) * 64, smem);
  }
}

// layer-2 aggregation (sample dsts only; proxy rows are dead code)
__global__ __launch_bounds__(NTHR) void agg2_k(
    const float* __restrict__ Es2, const float* __restrict__ h1,
    const float* __restrict__ esS2, const float* __restrict__ izS2,
    float* __restrict__ M2)
{
  __shared__ float smem[32 * 32 + 32 * 64];
  const int b = blockIdx.x;
  gemm_dev<32, 64, 2, 4, false, true>(
      Es2, NS, h1, PP, M2, nullptr, 128, DD,
      h1 + (size_t)PP * DD, esS2, izS2, (b >> 3) * 32, (b & 7) * 64, smem);
}

// ============ softmax weights (unnormalized exp), parallel reductions =======
// blocks [0,256): wave per sample dst -> Es[i][128] (cols 100..127 = 0), esS, izS
// blocks [256,256+np): block per proxy dst -> Ep[i][1024], esP, izP
__global__ __launch_bounds__(NTHR) void alpha_k(
    const float* __restrict__ ls, const float* __restrict__ ld,
    float* __restrict__ Es, float* __restrict__ esS, float* __restrict__ izS,
    float* __restrict__ Ep, float* __restrict__ esP, float* __restrict__ izP)
{
  const int t = threadIdx.x;
  if (blockIdx.x < 256) {
    const int lane = t & 63;
    const int i = blockIdx.x * 4 + (t >> 6);     // sample dst
    const float ldi = ld[PP + i];
    float e0 = lk(ls[lane] + ldi);               // lane < 100 always
    float e1 = (lane < PP - 64) ? lk(ls[lane + 64] + ldi) : -1e30f;
    const float eself = lk(ls[PP + i] + ldi);
    float m = fmaxf(fmaxf(e0, e1), eself);
    #pragma unroll
    for (int off = 1; off < 64; off <<= 1) m = fmaxf(m, __shfl_xor(m, off));
    float x0 = __expf(e0 - m);
    float x1 = (lane < PP - 64) ? __expf(e1 - m) : 0.f;
    float z = x0 + x1;
    #pragma unroll
    for (int off = 1; off < 64; off <<= 1) z += __shfl_xor(z, off);
    Es[(size_t)i * 128 + lane]      = x0;
    Es[(size_t)i * 128 + 64 + lane] = x1;
    if (lane == 0) {
      float xs = __expf(eself - m);
      esS[i] = xs;
      izS[i] = 1.f / (z + xs);
    }
  } else {
    const int i = blockIdx.x - 256;              // proxy dst
    __shared__ float red[4];
    const float ldi = ld[i];
    const float eself = lk(ls[i] + ldi);
    float e[4];
    #pragma unroll
    for (int q = 0; q < 4; ++q) e[q] = lk(ls[PP + t + q * 256] + ldi);
    float m = fmaxf(fmaxf(fmaxf(e[0], e[1]), fmaxf(e[2], e[3])), eself);
    #pragma unroll
    for (int off = 1; off < 64; off <<= 1) m = fmaxf(m, __shfl_xor(m, off));
    if ((t & 63) == 0) red[t >> 6] = m;
    __syncthreads();
    m = fmaxf(fmaxf(red[0], red[1]), fmaxf(red[2], red[3]));
    __syncthreads();
    float xq[4], z = 0.f;
    #pragma unroll
    for (int q = 0; q < 4; ++q) { xq[q] = __expf(e[q] - m); z += xq[q]; }
    #pragma unroll
    for (int off = 1; off < 64; off <<= 1) z += __shfl_xor(z, off);
    if ((t & 63) == 0) red[t >> 6] = z;
    __syncthreads();
    #pragma unroll
    for (int q = 0; q < 4; ++q) Ep[(size_t)i * NS + t + q * 256] = xq[q];
    if (t == 0) {
      float xs = __expf(eself - m);
      esP[i] = xs;
      izP[i] = 1.f / (red[0] + red[1] + red[2] + red[3] + xs);
    }
  }
}

// ============ v = W @ a for both layers (one wave per W row) ================
__global__ __launch_bounds__(NTHR) void matvec_k(
    const float* __restrict__ W1, const float* __restrict__ as1,
    const float* __restrict__ ad1,
    const float* __restrict__ W2, const float* __restrict__ as2,
    const float* __restrict__ ad2,
    float* __restrict__ v1s, float* __restrict__ v1d,
    float* __restrict__ v2s, float* __restrict__ v2d)
{
  const int wid  = blockIdx.x * 4 + (threadIdx.x >> 6);  // 0..1023
  const int lane = threadIdx.x & 63;
  const int r = wid & 511;
  const bool l1 = (wid < 512);
  const float* W = l1 ? W1 : W2;
  const float4* a4 = (const float4*)(l1 ? as1 : as2);
  const float4* b4 = (const float4*)(l1 ? ad1 : ad2);
  const float4* w4 = (const float4*)(W + (size_t)r * DD);
  float4 w0 = w4[lane], w1 = w4[lane + 64];
  float4 a0 = a4[lane], a1 = a4[lane + 64];
  float4 b0 = b4[lane], b1 = b4[lane + 64];
  float s1 = w0.x * a0.x + w0.y * a0.y + w0.z * a0.z + w0.w * a0.w
           + w1.x * a1.x + w1.y * a1.y + w1.z * a1.z + w1.w * a1.w;
  float s2 = w0.x * b0.x + w0.y * b0.y + w0.z * b0.z + w0.w * b0.w
           + w1.x * b1.x + w1.y * b1.y + w1.z * b1.z + w1.w * b1.w;
  #pragma unroll
  for (int off = 32; off > 0; off >>= 1) {
    s1 += __shfl_down(s1, off);
    s2 += __shfl_down(s2, off);
  }
  if (lane == 0) {
    (l1 ? v1s : v2s)[r] = s1;
    (l1 ? v1d : v2d)[r] = s2;
  }
}

// ============ logits: ls[r]=row_r.vs, ld[r]=row_r.vd (one wave per row) =====
__global__ __launch_bounds__(NTHR) void lvec_k(
    const float* __restrict__ A0, const float* __restrict__ A1, int split,
    const float* __restrict__ vs, const float* __restrict__ vd,
    float* __restrict__ ls, float* __restrict__ ld)
{
  const int r    = blockIdx.x * 4 + (threadIdx.x >> 6);
  const int lane = threadIdx.x & 63;
  if (r >= NN) return;
  const float* row = (r < split) ? A0 + (size_t)r * DD : A1 + (size_t)(r - split) * DD;
  const float4* r4 = (const float4*)row;
  const float4* s4 = (const float4*)vs;
  const float4* d4 = (const float4*)vd;
  float4 v0 = r4[lane], v1 = r4[lane + 64];
  float4 a0 = s4[lane], a1 = s4[lane + 64];
  float4 b0 = d4[lane], b1 = d4[lane + 64];
  float s1 = v0.x * a0.x + v0.y * a0.y + v0.z * a0.z + v0.w * a0.w
           + v1.x * a1.x + v1.y * a1.y + v1.z * a1.z + v1.w * a1.w;
  float s2 = v0.x * b0.x + v0.y * b0.y + v0.z * b0.z + v0.w * b0.w
           + v1.x * b1.x + v1.y * b1.y + v1.z * b1.z + v1.w * b1.w;
  #pragma unroll
  for (int off = 32; off > 0; off >>= 1) {
    s1 += __shfl_down(s1, off);
    s2 += __shfl_down(s2, off);
  }
  if (lane == 0) { ls[r] = s1; ld[r] = s2; }
}

extern "C" void kernel_launch(void* const* d_in, const int* in_sizes, int n_in,
                              void* d_out, int out_size, void* d_ws, size_t ws_size,
                              hipStream_t stream)
{
  const float* x    = (const float*)d_in[0];
  const float* prox = (const float*)d_in[1];
  const float* W1   = (const float*)d_in[2];
  const float* as1  = (const float*)d_in[3];
  const float* ad1  = (const float*)d_in[4];
  const float* b1   = (const float*)d_in[5];
  const float* W2   = (const float*)d_in[6];
  const float* as2  = (const float*)d_in[7];
  const float* ad2  = (const float*)d_in[8];
  const float* b2   = (const float*)d_in[9];
  const float* fcw  = (const float*)d_in[10];
  const float* fcb  = (const float*)d_in[11];
  float* out = (float*)d_out;

  float* h1   = (float*)d_ws;                    // [1124][512]
  float* M1   = h1   + (size_t)NN * DD;          // [1124][512]
  float* M2   = M1   + (size_t)NN * DD;          // [1024][512]
  float* Es1  = M2   + (size_t)NS * DD;          // [1024][128]
  float* Es2  = Es1  + (size_t)NS * 128;         // [1024][128]
  float* Ep   = Es2  + (size_t)NS * 128;         // [100][1024] (pad 128 rows)
  float* esS1 = Ep   + (size_t)128 * NS;
  float* izS1 = esS1 + NS;
  float* esS2 = izS1 + NS;
  float* izS2 = esS2 + NS;
  float* esP  = izS2 + NS;                       // [128]
  float* izP  = esP  + 128;                      // [128]
  float* ls1  = izP  + 128;                      // [1152]
  float* ld1  = ls1  + 1152;
  float* ls2  = ld1  + 1152;
  float* ld2  = ls2  + 1152;
  float* v1s  = ld2  + 1152;
  float* v1d  = v1s + DD;
  float* v2s  = v1d + DD;
  float* v2d  = v2s + DD;
  float* h2s  = out + (size_t)NS * CC;           // layer-2 sample out in d_out

  dim3 blk(NTHR);
  // 1: weight-side matvecs for both layers
  matvec_k<<<dim3(256), blk, 0, stream>>>(W1, as1, ad1, W2, as2, ad2,
                                          v1s, v1d, v2s, v2d);
  // 2: layer-1 logits
  lvec_k<<<dim3(281), blk, 0, stream>>>(prox, x, PP, v1s, v1d, ls1, ld1);
  // 3: layer-1 softmax weights (samples + proxies)
  alpha_k<<<dim3(256 + PP), blk, 0, stream>>>(ls1, ld1, Es1, esS1, izS1,
                                              Ep, esP, izP);
  // 4: layer-1 aggregation -> M1[1124][512]
  agg1_k<<<dim3(312), blk, 0, stream>>>(Es1, Ep, x, prox, esS1, izS1,
                                        esP, izP, M1);
  // 5: h1 = relu(M1@W1 + b1)
  gemm_k<32, 64, 2, true><<<dim3(8, 36), blk, 0, stream>>>(
      M1, NN, W1, h1, b1, DD, DD);
  // 6: layer-2 logits
  lvec_k<<<dim3(281), blk, 0, stream>>>(h1, h1, NN, v2s, v2d, ls2, ld2);
  // 7: layer-2 softmax weights (samples only)
  alpha_k<<<dim3(256), blk, 0, stream>>>(ls2, ld2, Es2, esS2, izS2,
                                         Ep, esP, izP);
  // 8: layer-2 aggregation -> M2[1024][512]
  agg2_k<<<dim3(256), blk, 0, stream>>>(Es2, h1, esS2, izS2, M2);
  // 9: h2s = relu(M2@W2 + b2) straight into d_out
  gemm_k<32, 64, 2, true><<<dim3(8, 32), blk, 0, stream>>>(
      M2, NS, W2, h2s, b2, DD, DD);
  // 10: preds = h2s @ fcw + fcb
  gemm_k<32, 64, 2, false><<<dim3(2, 32), blk, 0, stream>>>(
      h2s, NS, fcw, out, fcb, DD, CC);
}